// Round 2
// baseline (1016.817 us; speedup 1.0000x reference)
//
#include <hip/hip_runtime.h>

#define HID 128
#define SEQ 1024
#define NTHREADS 512
// h stored as 4 chunks of 32 floats, chunk stride 36 floats (144 B, 16B-aligned).
// Bank phase of chunk q = (q*36)%32 = 4q -> the 4 quad-lane ds_read_b128 addresses
// hit disjoint banks (was: 128B apart = same banks = 4-way conflict every load).
#define CH_STRIDE 36

// Quad (4-lane) all-reduce add via DPP quad_perm. Lanes 4j..4j+3 all end with
// the sum of their 4 values (bitwise-identical across lanes: commutative tree).
__device__ __forceinline__ float quad_reduce_add(float x) {
  union { float f; int i; } u, v;
  u.f = x;
  v.i = __builtin_amdgcn_update_dpp(0, u.i, 0xB1, 0xF, 0xF, true); // quad_perm(1,0,3,2)
  u.f += v.f;
  v.i = __builtin_amdgcn_update_dpp(0, u.i, 0x4E, 0xF, 0xF, true); // quad_perm(2,3,0,1)
  u.f += v.f;
  return u.f;
}

__device__ __forceinline__ float sigmoidf_(float x) {
  x = fminf(fmaxf(x, -30.f), 30.f);
  float e = __expf(-x);
  return __builtin_amdgcn_rcpf(1.f + e);
}

__device__ __forceinline__ float tanhf_(float x) {
  x = fminf(fmaxf(x, -15.f), 15.f);
  float e = __expf(-2.f * x);
  return (1.f - e) * __builtin_amdgcn_rcpf(1.f + e);
}

__global__ __launch_bounds__(NTHREADS, 1)  // 1 wave/EU min -> allow full VGPR file
void gru_kernel(const float* __restrict__ x,     // [B, S, 1]
                const float* __restrict__ w_ih,  // [3H, 1]
                const float* __restrict__ w_hh,  // [3H, H]
                const float* __restrict__ b_ih,  // [3H]
                const float* __restrict__ b_hh,  // [3H]
                const float* __restrict__ w_fc,  // [1, H]
                const float* __restrict__ b_fc,  // [1]
                float* __restrict__ out)         // [B, 1]
{
  __shared__ float xs[SEQ];
  __shared__ float hbuf[2][4 * CH_STRIDE];
  __shared__ float red[8];

  const int t = threadIdx.x;
  const int b = blockIdx.x;
  const int j = t >> 2;   // hidden unit
  const int q = t & 3;    // k-quarter

  // stage x[b, :] into LDS (coalesced)
  const float* xrow = x + (size_t)b * SEQ;
  for (int i = t; i < SEQ; i += NTHREADS) xs[i] = xrow[i];
  if (t < HID) hbuf[0][(t >> 5) * CH_STRIDE + (t & 31)] = 0.f;

  // W_hh slices for rows j (r), H+j (z), 2H+j (n), cols [q*32, q*32+32)
  float4 wr[8], wz[8], wn[8];
  {
    const float4* pr = (const float4*)(w_hh + (size_t)j * HID + q * 32);
    const float4* pz = (const float4*)(w_hh + (size_t)(HID + j) * HID + q * 32);
    const float4* pn = (const float4*)(w_hh + (size_t)(2 * HID + j) * HID + q * 32);
#pragma unroll
    for (int k = 0; k < 8; ++k) { wr[k] = pr[k]; wz[k] = pz[k]; wn[k] = pn[k]; }
  }
  const float bhr = b_hh[j], bhz = b_hh[HID + j], bhn = b_hh[2 * HID + j];
  const float wir = w_ih[j], wiz = w_ih[HID + j], win = w_ih[2 * HID + j];
  const float bir = b_ih[j], biz = b_ih[HID + j], bin = b_ih[2 * HID + j];

  const int wchunk = (j >> 5) * CH_STRIDE + (j & 31);  // where lane q==0 writes h_j

  float hprev = 0.f;
  int cur = 0;
  __syncthreads();

  for (int s = 0; s < SEQ; ++s) {
    const float xt = xs[s];
    const float4* hp = (const float4*)(hbuf[cur] + q * CH_STRIDE);
    float4 ar = make_float4(0.f, 0.f, 0.f, 0.f);
    float4 az = make_float4(0.f, 0.f, 0.f, 0.f);
    float4 an = make_float4(0.f, 0.f, 0.f, 0.f);
#pragma unroll
    for (int k = 0; k < 8; ++k) {
      float4 hv = hp[k];
      ar.x = fmaf(wr[k].x, hv.x, ar.x);
      ar.y = fmaf(wr[k].y, hv.y, ar.y);
      ar.z = fmaf(wr[k].z, hv.z, ar.z);
      ar.w = fmaf(wr[k].w, hv.w, ar.w);
      az.x = fmaf(wz[k].x, hv.x, az.x);
      az.y = fmaf(wz[k].y, hv.y, az.y);
      az.z = fmaf(wz[k].z, hv.z, az.z);
      az.w = fmaf(wz[k].w, hv.w, az.w);
      an.x = fmaf(wn[k].x, hv.x, an.x);
      an.y = fmaf(wn[k].y, hv.y, an.y);
      an.z = fmaf(wn[k].z, hv.z, an.z);
      an.w = fmaf(wn[k].w, hv.w, an.w);
    }
    float dr = (ar.x + ar.y) + (ar.z + ar.w);
    float dz = (az.x + az.y) + (az.z + az.w);
    float dn = (an.x + an.y) + (an.z + an.w);
    dr = quad_reduce_add(dr);
    dz = quad_reduce_add(dz);
    dn = quad_reduce_add(dn);

    const float r = sigmoidf_(fmaf(xt, wir, bir) + dr + bhr);
    const float z = sigmoidf_(fmaf(xt, wiz, biz) + dz + bhz);
    const float n = tanhf_(fmaf(xt, win, bin) + r * (dn + bhn));
    const float hnew = n + z * (hprev - n);
    hprev = hnew;
    if (q == 0) hbuf[cur ^ 1][wchunk] = hnew;
    cur ^= 1;
    __syncthreads();
  }

  // epilogue: out[b] = relu(h_T) . w_fc + b_fc
  float v = (q == 0) ? fmaxf(hprev, 0.f) * w_fc[j] : 0.f;
#pragma unroll
  for (int off = 1; off < 64; off <<= 1) v += __shfl_xor(v, off);
  if ((t & 63) == 0) red[t >> 6] = v;
  __syncthreads();
  if (t == 0) {
    float sum = 0.f;
#pragma unroll
    for (int w = 0; w < 8; ++w) sum += red[w];
    out[b] = sum + b_fc[0];
  }
}

extern "C" void kernel_launch(void* const* d_in, const int* in_sizes, int n_in,
                              void* d_out, int out_size, void* d_ws, size_t ws_size,
                              hipStream_t stream) {
  const float* x    = (const float*)d_in[0];
  const float* w_ih = (const float*)d_in[1];
  const float* w_hh = (const float*)d_in[2];
  const float* b_ih = (const float*)d_in[3];
  const float* b_hh = (const float*)d_in[4];
  const float* w_fc = (const float*)d_in[5];
  const float* b_fc = (const float*)d_in[6];
  gru_kernel<<<256, NTHREADS, 0, stream>>>(x, w_ih, w_hh, b_ih, b_hh, w_fc, b_fc,
                                           (float*)d_out);
}

// Round 3
// 857.877 us; speedup vs baseline: 1.1853x; 1.1853x over previous
//
#include <hip/hip_runtime.h>

#define HID 128
#define SEQ 1024
#define NT 1024
// h stored as 8 chunks of 16 floats, chunk stride 20 floats (80 B, 16B-aligned).
// Bank phase of chunk o = (20*o)%32 = {0,20,8,28,16,4,24,12} -> the 8 distinct
// ds_read_b128 addresses per wave cover all 32 banks exactly once: conflict-free.
#define CH 20

__device__ __forceinline__ float xor1_add(float x) {
  union { float f; int i; } u, v;
  u.f = x;
  v.i = __builtin_amdgcn_update_dpp(0, u.i, 0xB1, 0xF, 0xF, true); // quad_perm(1,0,3,2)
  return u.f + v.f;
}
__device__ __forceinline__ float xor2_add(float x) {
  union { float f; int i; } u, v;
  u.f = x;
  v.i = __builtin_amdgcn_update_dpp(0, u.i, 0x4E, 0xF, 0xF, true); // quad_perm(2,3,0,1)
  return u.f + v.f;
}
__device__ __forceinline__ float xor4_add(float x) {
  union { float f; int i; } u, v;
  u.f = x;
  v.i = __builtin_amdgcn_ds_swizzle(u.i, 0x101F); // BitMode: xor 4, and 0x1F
  return u.f + v.f;
}
// 8-lane all-reduce within lane groups 8m..8m+7
__device__ __forceinline__ float red8(float x) {
  return xor4_add(xor2_add(xor1_add(x)));
}

__device__ __forceinline__ float sigmoidf_(float x) {
  x = __builtin_amdgcn_fmed3f(x, -30.f, 30.f);
  float e = __expf(-x);
  return __builtin_amdgcn_rcpf(1.f + e);
}
__device__ __forceinline__ float tanhf_(float x) {
  x = __builtin_amdgcn_fmed3f(x, -15.f, 15.f);
  float e = __expf(-2.f * x);
  return (1.f - e) * __builtin_amdgcn_rcpf(1.f + e);
}

__global__ __launch_bounds__(NT, 4)  // 16 waves/CU, cap 128 VGPR (fills reg file)
void gru_kernel(const float* __restrict__ x,     // [B, S, 1]
                const float* __restrict__ w_ih,  // [3H, 1]
                const float* __restrict__ w_hh,  // [3H, H]
                const float* __restrict__ b_ih,  // [3H]
                const float* __restrict__ b_hh,  // [3H]
                const float* __restrict__ w_fc,  // [1, H]
                const float* __restrict__ b_fc,  // [1]
                float* __restrict__ out)         // [B, 1]
{
  __shared__ float xs[SEQ];
  __shared__ float hbuf[2][8 * CH];
  __shared__ float red[16];

  const int t = threadIdx.x;
  const int b = blockIdx.x;
  const int j = t >> 3;   // hidden unit 0..127
  const int o = t & 7;    // k-eighth: cols [16o, 16o+16)

  const float* xrow = x + (size_t)b * SEQ;
  for (int i = t; i < SEQ; i += NT) xs[i] = xrow[i];
  if (t < HID) hbuf[0][(t >> 4) * CH + (t & 15)] = 0.f;

  // W_hh slices: rows j (r), H+j (z), 2H+j (n), cols [16o, 16o+16)
  float4 wr[4], wz[4], wn[4];
  {
    const float4* pr = (const float4*)(w_hh + (size_t)j * HID + o * 16);
    const float4* pz = (const float4*)(w_hh + (size_t)(HID + j) * HID + o * 16);
    const float4* pn = (const float4*)(w_hh + (size_t)(2 * HID + j) * HID + o * 16);
#pragma unroll
    for (int k = 0; k < 4; ++k) { wr[k] = pr[k]; wz[k] = pz[k]; wn[k] = pn[k]; }
  }
  const float bcr = b_ih[j] + b_hh[j];                       // combined r bias
  const float bcz = b_ih[HID + j] + b_hh[HID + j];           // combined z bias
  const float bin_ = b_ih[2 * HID + j], bhn = b_hh[2 * HID + j];
  const float wir = w_ih[j], wiz = w_ih[HID + j], win = w_ih[2 * HID + j];

  const int widx = (j >> 4) * CH + (j & 15);  // where lane o==0 writes h_j

  float hprev = 0.f;
  int cur = 0;
  __syncthreads();

  for (int s = 0; s < SEQ; ++s) {
    const float xt = xs[s];
    const float4* hp = (const float4*)(hbuf[cur] + o * CH);
    float4 ar = make_float4(0.f, 0.f, 0.f, 0.f);
    float4 az = make_float4(0.f, 0.f, 0.f, 0.f);
    float4 an = make_float4(0.f, 0.f, 0.f, 0.f);
#pragma unroll
    for (int k = 0; k < 4; ++k) {
      float4 hv = hp[k];
      ar.x = fmaf(wr[k].x, hv.x, ar.x);
      ar.y = fmaf(wr[k].y, hv.y, ar.y);
      ar.z = fmaf(wr[k].z, hv.z, ar.z);
      ar.w = fmaf(wr[k].w, hv.w, ar.w);
      az.x = fmaf(wz[k].x, hv.x, az.x);
      az.y = fmaf(wz[k].y, hv.y, az.y);
      az.z = fmaf(wz[k].z, hv.z, az.z);
      az.w = fmaf(wz[k].w, hv.w, az.w);
      an.x = fmaf(wn[k].x, hv.x, an.x);
      an.y = fmaf(wn[k].y, hv.y, an.y);
      an.z = fmaf(wn[k].z, hv.z, an.z);
      an.w = fmaf(wn[k].w, hv.w, an.w);
    }
    float dr = (ar.x + ar.y) + (ar.z + ar.w);
    float dz = (az.x + az.y) + (az.z + az.w);
    float dn = (an.x + an.y) + (an.z + an.w);
    dr = red8(dr);
    dz = red8(dz);
    dn = red8(dn);

    const float r = sigmoidf_(fmaf(xt, wir, bcr) + dr);
    const float z = sigmoidf_(fmaf(xt, wiz, bcz) + dz);
    const float n = tanhf_(fmaf(xt, win, bin_) + r * (dn + bhn));
    const float hnew = n + z * (hprev - n);
    hprev = hnew;
    if (o == 0) hbuf[cur ^ 1][widx] = hnew;
    cur ^= 1;
    __syncthreads();
  }

  // epilogue: out[b] = relu(h_T) . w_fc + b_fc
  float v = (o == 0) ? fmaxf(hprev, 0.f) * w_fc[j] : 0.f;
#pragma unroll
  for (int off = 1; off < 64; off <<= 1) v += __shfl_xor(v, off);
  if ((t & 63) == 0) red[t >> 6] = v;
  __syncthreads();
  if (t == 0) {
    float sum = 0.f;
#pragma unroll
    for (int w = 0; w < 16; ++w) sum += red[w];
    out[b] = sum + b_fc[0];
  }
}

extern "C" void kernel_launch(void* const* d_in, const int* in_sizes, int n_in,
                              void* d_out, int out_size, void* d_ws, size_t ws_size,
                              hipStream_t stream) {
  const float* x    = (const float*)d_in[0];
  const float* w_ih = (const float*)d_in[1];
  const float* w_hh = (const float*)d_in[2];
  const float* b_ih = (const float*)d_in[3];
  const float* b_hh = (const float*)d_in[4];
  const float* w_fc = (const float*)d_in[5];
  const float* b_fc = (const float*)d_in[6];
  gru_kernel<<<256, NT, 0, stream>>>(x, w_ih, w_hh, b_ih, b_hh, w_fc, b_fc,
                                     (float*)d_out);
}

// Round 4
// 796.040 us; speedup vs baseline: 1.2773x; 1.0777x over previous
//
#include <hip/hip_runtime.h>

#define SEQ 1024
#define NT 512   // 8 waves; wave w owns gate-preact cols [16w,16w+16) for r,z,n

typedef __attribute__((ext_vector_type(8))) short short8;  // 8 bf16 (4 VGPRs)
typedef __attribute__((ext_vector_type(4))) float f32x4;   // MFMA 16x16 accum

// fp32 -> bf16 (round-to-nearest-even), bit trick valid for all finite inputs
__device__ __forceinline__ short f2bf(float f) {
  union { float f; unsigned u; } x; x.f = f;
  unsigned r = (x.u + 0x7FFFu + ((x.u >> 16) & 1u)) >> 16;
  return (short)r;
}
__device__ __forceinline__ float bf2f(short h) {
  union { float f; unsigned u; } x; x.u = ((unsigned)(unsigned short)h) << 16;
  return x.f;
}

__device__ __forceinline__ float sigmoidf_(float x) {
  x = __builtin_amdgcn_fmed3f(x, -30.f, 30.f);
  float e = __expf(-x);
  return __builtin_amdgcn_rcpf(1.f + e);
}
__device__ __forceinline__ float tanhf_(float x) {
  x = __builtin_amdgcn_fmed3f(x, -15.f, 15.f);
  float e = __expf(-2.f * x);
  return (1.f - e) * __builtin_amdgcn_rcpf(1.f + e);
}

__global__ __launch_bounds__(NT, 2)  // 256-VGPR budget; ~1 block/CU by design
void gru_kernel(const float* __restrict__ x,     // [B, S, 1]
                const float* __restrict__ w_ih,  // [3H, 1]
                const float* __restrict__ w_hh,  // [3H, H]
                const float* __restrict__ b_ih,  // [3H]
                const float* __restrict__ b_hh,  // [3H]
                const float* __restrict__ w_fc,  // [1, H]
                const float* __restrict__ b_fc,  // [1]
                float* __restrict__ out)         // [B, 1]
{
  __shared__ float xs[SEQ];
  __shared__ __align__(16) short hhi[2][128];  // h as bf16 hi
  __shared__ __align__(16) short hlo[2][128];  // h residual as bf16 lo
  __shared__ float red[8];

  const int t = threadIdx.x;
  const int b = blockIdx.x;
  const int w = t >> 6;          // wave 0..7
  const int L = t & 63;          // lane
  const int n = L & 15;          // MFMA col within tile
  const int quad = L >> 4;       // MFMA k-slice / row-group
  const int u = 16 * w + n;      // hidden unit this lane's cols correspond to

  // stage x[b,:] (coalesced)
  const float* xrow = x + (size_t)b * SEQ;
  for (int i = t; i < SEQ; i += NT) xs[i] = xrow[i];
  if (t < 128) { hhi[0][t] = 0; hlo[0][t] = 0; }

  // --- B fragments (persistent): B[k = quad*8+i][col = n] = W_hh^T[k][g*128+u]
  //     = w_hh[(g*128+u)*128 + k].  hi/lo bf16 split for ~17-bit precision.
  short8 Bhi[3][4], Blo[3][4];   // [gate r/z/n][ktile]; MFMA reads AGPRs natively
#pragma unroll
  for (int g = 0; g < 3; ++g) {
    const float* row = w_hh + (size_t)(g * 128 + u) * 128;
#pragma unroll
    for (int kt = 0; kt < 4; ++kt) {
      union { short s[8]; short8 v; } hi, lo;
#pragma unroll
      for (int i = 0; i < 8; ++i) {
        float wv = row[kt * 32 + quad * 8 + i];
        short h = f2bf(wv);
        hi.s[i] = h;
        lo.s[i] = f2bf(wv - bf2f(h));
      }
      Bhi[g][kt] = hi.v;
      Blo[g][kt] = lo.v;
    }
  }
  const float bcr  = b_ih[u] + b_hh[u];               // combined r bias
  const float bcz  = b_ih[128 + u] + b_hh[128 + u];   // combined z bias
  const float bin_ = b_ih[256 + u], bhn = b_hh[256 + u];
  const float wir = w_ih[u], wiz = w_ih[128 + u], win = w_ih[256 + u];

  float hprev = 0.f;   // h[u], replicated across the 4 quads (identical math)
  int cur = 0;
  __syncthreads();

#define MF(A, B, C) C = __builtin_amdgcn_mfma_f32_16x16x32_bf16(A, B, C, 0, 0, 0)

  for (int s = 0; s < SEQ; ++s) {
    const float xt = xs[s];
    // A fragments: broadcast h into all 16 rows (addr independent of lane&15)
    // lane element i = h[kt*32 + quad*8 + i]; 4 distinct 16B addrs -> conflict-free
    short8 Ahi[4], Alo[4];
#pragma unroll
    for (int kt = 0; kt < 4; ++kt) {
      Ahi[kt] = *(const short8*)&hhi[cur][kt * 32 + quad * 8];
      Alo[kt] = *(const short8*)&hlo[cur][kt * 32 + quad * 8];
    }
    f32x4 zero = {0.f, 0.f, 0.f, 0.f};
    f32x4 ar0 = zero, ar1 = zero, az0 = zero, az1 = zero, an0 = zero, an1 = zero;
    // 36 MFMAs: 3 gates x 4 ktiles x (hi*hi + lo*hi + hi*lo); kt 0-1 -> acc0,
    // kt 2-3 -> acc1 (6 chains of depth 6 for MFMA-pipe ILP)
#pragma unroll
    for (int kt = 0; kt < 2; ++kt) {
      MF(Ahi[kt], Bhi[0][kt], ar0);
      MF(Ahi[kt], Bhi[1][kt], az0);
      MF(Ahi[kt], Bhi[2][kt], an0);
      MF(Alo[kt], Bhi[0][kt], ar0);
      MF(Alo[kt], Bhi[1][kt], az0);
      MF(Alo[kt], Bhi[2][kt], an0);
      MF(Ahi[kt], Blo[0][kt], ar0);
      MF(Ahi[kt], Blo[1][kt], az0);
      MF(Ahi[kt], Blo[2][kt], an0);
    }
#pragma unroll
    for (int kt = 2; kt < 4; ++kt) {
      MF(Ahi[kt], Bhi[0][kt], ar1);
      MF(Ahi[kt], Bhi[1][kt], az1);
      MF(Ahi[kt], Bhi[2][kt], an1);
      MF(Alo[kt], Bhi[0][kt], ar1);
      MF(Alo[kt], Bhi[1][kt], az1);
      MF(Alo[kt], Bhi[2][kt], an1);
      MF(Ahi[kt], Blo[0][kt], ar1);
      MF(Ahi[kt], Blo[1][kt], az1);
      MF(Ahi[kt], Blo[2][kt], an1);
    }
    // all D rows identical (A rows identical) -> element 0 is this col's dot
    const float dr = ar0[0] + ar1[0];
    const float dz = az0[0] + az1[0];
    const float dn = an0[0] + an1[0];

    const float r  = sigmoidf_(fmaf(xt, wir, bcr) + dr);
    const float z  = sigmoidf_(fmaf(xt, wiz, bcz) + dz);
    const float nn = tanhf_(fmaf(xt, win, bin_) + r * (dn + bhn));
    hprev = nn + z * (hprev - nn);

    const short hib = f2bf(hprev);
    const short lob = f2bf(hprev - bf2f(hib));
    if (quad == 0) {               // one writer per unit
      hhi[cur ^ 1][u] = hib;
      hlo[cur ^ 1][u] = lob;
    }
    cur ^= 1;
    __syncthreads();
  }

  // epilogue: out[b] = relu(h_T) . w_fc + b_fc
  float v = (quad == 0) ? fmaxf(hprev, 0.f) * w_fc[u] : 0.f;
#pragma unroll
  for (int off = 1; off < 64; off <<= 1) v += __shfl_xor(v, off);
  if (L == 0) red[w] = v;
  __syncthreads();
  if (t == 0) {
    float sum = 0.f;
#pragma unroll
    for (int k = 0; k < 8; ++k) sum += red[k];
    out[b] = sum + b_fc[0];
  }
}

extern "C" void kernel_launch(void* const* d_in, const int* in_sizes, int n_in,
                              void* d_out, int out_size, void* d_ws, size_t ws_size,
                              hipStream_t stream) {
  const float* x    = (const float*)d_in[0];
  const float* w_ih = (const float*)d_in[1];
  const float* w_hh = (const float*)d_in[2];
  const float* b_ih = (const float*)d_in[3];
  const float* b_hh = (const float*)d_in[4];
  const float* w_fc = (const float*)d_in[5];
  const float* b_fc = (const float*)d_in[6];
  gru_kernel<<<256, NT, 0, stream>>>(x, w_ih, w_hh, b_ih, b_hh, w_fc, b_fc,
                                     (float*)d_out);
}

// Round 5
// 501.705 us; speedup vs baseline: 2.0267x; 1.5867x over previous
//
#include <hip/hip_runtime.h>

#define SEQ 1024
#define NT 512   // 8 waves; wave w owns gate-preact cols [16w,16w+16) for r,z,n

typedef _Float16 half8 __attribute__((ext_vector_type(8)));  // 4 VGPRs
typedef float f32x4 __attribute__((ext_vector_type(4)));     // MFMA 16x16 accum

__device__ __forceinline__ float sigmoidf_(float x) {
  x = __builtin_amdgcn_fmed3f(x, -30.f, 30.f);
  float e = __expf(-x);
  return __builtin_amdgcn_rcpf(1.f + e);
}
__device__ __forceinline__ float tanhf_(float x) {
  x = __builtin_amdgcn_fmed3f(x, -15.f, 15.f);
  float e = __expf(-2.f * x);
  return (1.f - e) * __builtin_amdgcn_rcpf(1.f + e);
}

__global__ __launch_bounds__(NT, 2)
void gru_kernel(const float* __restrict__ x,     // [B, S, 1]
                const float* __restrict__ w_ih,  // [3H, 1]
                const float* __restrict__ w_hh,  // [3H, H]
                const float* __restrict__ b_ih,  // [3H]
                const float* __restrict__ b_hh,  // [3H]
                const float* __restrict__ w_fc,  // [1, H]
                const float* __restrict__ b_fc,  // [1]
                float* __restrict__ out)         // [B, 1]
{
  __shared__ float xs[SEQ];
  __shared__ __align__(16) _Float16 hs[2][2][128];  // [buf][0=h_hi,1=h_lo][unit]
  __shared__ float red[8];

  const int t = threadIdx.x;
  const int b = blockIdx.x;
  const int w = t >> 6;          // wave 0..7
  const int L = t & 63;          // lane
  const int n = L & 15;          // MFMA col (unit within wave's tile); also A-row m
  const int quad = L >> 4;       // k-slice / C-row group
  const int u = 16 * w + n;      // hidden unit
  const int hl = n >> 3;         // A rows 0-7 carry h_hi, rows 8-15 carry h_lo

  // stage x[b,:] (coalesced)
  const float* xrow = x + (size_t)b * SEQ;
  for (int i = t; i < SEQ; i += NT) xs[i] = xrow[i];
  if (t < 256) (&hs[0][0][0])[t] = (_Float16)0.f;

  // B fragments (persistent, fp16): B[k=quad*8+i][col=n] = w_hh[(g*128+u)*128 + k]
  half8 Bw[3][4];
#pragma unroll
  for (int g = 0; g < 3; ++g) {
    const float* row = w_hh + (size_t)(g * 128 + u) * 128;
#pragma unroll
    for (int kt = 0; kt < 4; ++kt) {
      union { _Float16 s[8]; half8 v; } tmp;
#pragma unroll
      for (int i = 0; i < 8; ++i) tmp.s[i] = (_Float16)row[kt * 32 + quad * 8 + i];
      Bw[g][kt] = tmp.v;
    }
  }
  const float bcr  = b_ih[u] + b_hh[u];
  const float bcz  = b_ih[128 + u] + b_hh[128 + u];
  const float bin_ = b_ih[256 + u], bhn = b_hh[256 + u];
  const float wir = w_ih[u], wiz = w_ih[128 + u], win = w_ih[256 + u];

  float hprev = 0.f;   // h[u], replicated across quads (identical math)
  __syncthreads();

#define MF(A, B, C) C = __builtin_amdgcn_mfma_f32_16x16x32_f16(A, B, C, 0, 0, 0)

  // One step: read buf RD, write buf WR. A rows 0-7 = h_hi, 8-15 = h_lo ->
  // one MFMA yields hi-dot (quads 0,1) and lo-dot (quads 2,3); shfl_xor(32) sums.
#define STEP(RD, WR, XT)                                                       \
  {                                                                            \
    const float xt = (XT);                                                     \
    half8 A[4];                                                                \
    _Pragma("unroll")                                                          \
    for (int kt = 0; kt < 4; ++kt)                                             \
      A[kt] = *(const half8*)&hs[RD][hl][kt * 32 + quad * 8];                  \
    f32x4 ar = {0.f, 0.f, 0.f, 0.f};                                           \
    f32x4 az = {0.f, 0.f, 0.f, 0.f};                                           \
    f32x4 an = {0.f, 0.f, 0.f, 0.f};                                           \
    _Pragma("unroll")                                                          \
    for (int kt = 0; kt < 4; ++kt) {                                           \
      MF(A[kt], Bw[0][kt], ar);                                                \
      MF(A[kt], Bw[1][kt], az);                                                \
      MF(A[kt], Bw[2][kt], an);                                                \
    }                                                                          \
    const float dr = ar[0] + __shfl_xor(ar[0], 32, 64);                        \
    const float dz = az[0] + __shfl_xor(az[0], 32, 64);                        \
    const float dn = an[0] + __shfl_xor(an[0], 32, 64);                        \
    const float r  = sigmoidf_(fmaf(xt, wir, bcr) + dr);                       \
    const float z  = sigmoidf_(fmaf(xt, wiz, bcz) + dz);                       \
    const float nn = tanhf_(fmaf(xt, win, bin_) + r * (dn + bhn));             \
    hprev = nn + z * (hprev - nn);                                             \
    const _Float16 hih = (_Float16)hprev;                                      \
    const _Float16 loh = (_Float16)(hprev - (float)hih);                       \
    if (quad == 0) { hs[WR][0][u] = hih; hs[WR][1][u] = loh; }                 \
    __syncthreads();                                                           \
  }

  for (int s = 0; s < SEQ; s += 2) {
    STEP(0, 1, xs[s]);
    STEP(1, 0, xs[s + 1]);
  }
#undef STEP
#undef MF

  // epilogue: out[b] = relu(h_T) . w_fc + b_fc
  float v = (quad == 0) ? fmaxf(hprev, 0.f) * w_fc[u] : 0.f;
#pragma unroll
  for (int off = 1; off < 64; off <<= 1) v += __shfl_xor(v, off);
  if (L == 0) red[w] = v;
  __syncthreads();
  if (t == 0) {
    float sum = 0.f;
#pragma unroll
    for (int k = 0; k < 8; ++k) sum += red[k];
    out[b] = sum + b_fc[0];
  }
}

extern "C" void kernel_launch(void* const* d_in, const int* in_sizes, int n_in,
                              void* d_out, int out_size, void* d_ws, size_t ws_size,
                              hipStream_t stream) {
  const float* x    = (const float*)d_in[0];
  const float* w_ih = (const float*)d_in[1];
  const float* w_hh = (const float*)d_in[2];
  const float* b_ih = (const float*)d_in[3];
  const float* b_hh = (const float*)d_in[4];
  const float* w_fc = (const float*)d_in[5];
  const float* b_fc = (const float*)d_in[6];
  gru_kernel<<<256, NT, 0, stream>>>(x, w_ih, w_hh, b_ih, b_hh, w_fc, b_fc,
                                     (float*)d_out);
}

// Round 6
// 429.250 us; speedup vs baseline: 2.3688x; 1.1688x over previous
//
#include <hip/hip_runtime.h>

#define SEQ 1024
#define NT 512   // 8 waves; wave w owns gate-preact cols [16w,16w+16) for r,z,n

typedef _Float16 half8 __attribute__((ext_vector_type(8)));  // 4 VGPRs
typedef float f32x4 __attribute__((ext_vector_type(4)));     // MFMA 16x16 accum

// h buffer layout (halfwords): [buf][0..127]=h_hi, [buf][160..287]=h_lo.
// lo offset 160 hw = 80 words = bank shift 16 -> a wave's 8 distinct A-read
// addresses (hl in {0,1} x quad in {0..3}) cover all 32 banks exactly once.
#define LO_OFF 160
#define HBUF 320

__device__ __forceinline__ float sigmoidf_(float x) {
  float e = __expf(-x);
  return __builtin_amdgcn_rcpf(1.f + e);
}
__device__ __forceinline__ float tanhf_(float x) {
  float e = __expf(-2.f * x);
  return (1.f - e) * __builtin_amdgcn_rcpf(1.f + e);
}

__global__ __launch_bounds__(NT, 2)
void gru_kernel(const float* __restrict__ x,     // [B, S, 1]
                const float* __restrict__ w_ih,  // [3H, 1]
                const float* __restrict__ w_hh,  // [3H, H]
                const float* __restrict__ b_ih,  // [3H]
                const float* __restrict__ b_hh,  // [3H]
                const float* __restrict__ w_fc,  // [1, H]
                const float* __restrict__ b_fc,  // [1]
                float* __restrict__ out)         // [B, 1]
{
  __shared__ float xs[SEQ];
  __shared__ __align__(16) _Float16 hs[2][HBUF];
  __shared__ float red[8];

  const int t = threadIdx.x;
  const int b = blockIdx.x;
  const int w = t >> 6;          // wave 0..7
  const int L = t & 63;          // lane
  const int n = L & 15;          // MFMA col (unit in tile) == A-row m
  const int quad = L >> 4;       // k-slice / C-row group
  const int u = 16 * w + n;      // hidden unit
  const int hl = n & 1;          // A-row parity: even rows = h_hi, odd = h_lo

  // stage x[b,:] (coalesced)
  const float* xrow = x + (size_t)b * SEQ;
  for (int i = t; i < SEQ; i += NT) xs[i] = xrow[i];
  if (t < HBUF) hs[0][t] = (_Float16)0.f;

  // B fragments (persistent, fp16): B[k=quad*8+i][col=n] = w_hh[(g*128+u)*128 + k]
  half8 Bw[3][4];
#pragma unroll
  for (int g = 0; g < 3; ++g) {
    const float* row = w_hh + (size_t)(g * 128 + u) * 128;
#pragma unroll
    for (int kt = 0; kt < 4; ++kt) {
      union { _Float16 s[8]; half8 v; } tmp;
#pragma unroll
      for (int i = 0; i < 8; ++i) tmp.s[i] = (_Float16)row[kt * 32 + quad * 8 + i];
      Bw[g][kt] = tmp.v;
    }
  }
  const float bcr  = b_ih[u] + b_hh[u];
  const float bcz  = b_ih[128 + u] + b_hh[128 + u];
  const float bin_ = b_ih[256 + u], bhn = b_hh[256 + u];
  const float wir = w_ih[u], wiz = w_ih[128 + u], win = w_ih[256 + u];

  // per-lane A-read base (halfwords): parity-selected hi/lo bank group
  const int abase = hl * LO_OFF + quad * 8;

  float hprev = 0.f;   // h[u], replicated across quads (identical math)
  __syncthreads();

#define MF(A, B, C) C = __builtin_amdgcn_mfma_f32_16x16x32_f16(A, B, C, 0, 0, 0)

  // One step: read buf RD, write buf WR. A even rows = h_hi, odd rows = h_lo.
  // C reg0 = rows {0,4,8,12} (hi-dot), reg1 = rows {1,5,9,13} (lo-dot):
  // d = C[0] + C[1] in-lane, no cross-lane reduction needed.
#define STEP(RD, WR, XT)                                                       \
  {                                                                            \
    const float xt = (XT);                                                     \
    half8 A[4];                                                                \
    _Pragma("unroll")                                                          \
    for (int kt = 0; kt < 4; ++kt)                                             \
      A[kt] = *(const half8*)&hs[RD][abase + kt * 32];                         \
    f32x4 ar = {0.f, 0.f, 0.f, 0.f};                                           \
    f32x4 az = {0.f, 0.f, 0.f, 0.f};                                           \
    f32x4 an = {0.f, 0.f, 0.f, 0.f};                                           \
    _Pragma("unroll")                                                          \
    for (int kt = 0; kt < 4; ++kt) {                                           \
      MF(A[kt], Bw[0][kt], ar);                                                \
      MF(A[kt], Bw[1][kt], az);                                                \
      MF(A[kt], Bw[2][kt], an);                                                \
    }                                                                          \
    const float dr = ar[0] + ar[1];                                            \
    const float dz = az[0] + az[1];                                            \
    const float dn = an[0] + an[1];                                            \
    const float r  = sigmoidf_(fmaf(xt, wir, bcr) + dr);                       \
    const float z  = sigmoidf_(fmaf(xt, wiz, bcz) + dz);                       \
    const float nn = tanhf_(fmaf(xt, win, bin_) + r * (dn + bhn));             \
    hprev = nn + z * (hprev - nn);                                             \
    const _Float16 hih = (_Float16)hprev;                                      \
    const _Float16 loh = (_Float16)(hprev - (float)hih);                       \
    if (quad == 0) { hs[WR][u] = hih; hs[WR][LO_OFF + u] = loh; }              \
    __syncthreads();                                                           \
  }

  for (int s = 0; s < SEQ; s += 2) {
    STEP(0, 1, xs[s]);
    STEP(1, 0, xs[s + 1]);
  }
#undef STEP
#undef MF

  // epilogue: out[b] = relu(h_T) . w_fc + b_fc
  float v = (quad == 0) ? fmaxf(hprev, 0.f) * w_fc[u] : 0.f;
#pragma unroll
  for (int off = 1; off < 64; off <<= 1) v += __shfl_xor(v, off);
  if (L == 0) red[w] = v;
  __syncthreads();
  if (t == 0) {
    float sum = 0.f;
#pragma unroll
    for (int k = 0; k < 8; ++k) sum += red[k];
    out[b] = sum + b_fc[0];
  }
}

extern "C" void kernel_launch(void* const* d_in, const int* in_sizes, int n_in,
                              void* d_out, int out_size, void* d_ws, size_t ws_size,
                              hipStream_t stream) {
  const float* x    = (const float*)d_in[0];
  const float* w_ih = (const float*)d_in[1];
  const float* w_hh = (const float*)d_in[2];
  const float* b_ih = (const float*)d_in[3];
  const float* b_hh = (const float*)d_in[4];
  const float* w_fc = (const float*)d_in[5];
  const float* b_fc = (const float*)d_in[6];
  gru_kernel<<<256, NT, 0, stream>>>(x, w_ih, w_hh, b_ih, b_hh, w_fc, b_fc,
                                     (float*)d_out);
}